// Round 15
// baseline (270.293 us; speedup 1.0000x reference)
//
#include <hip/hip_runtime.h>

// FrequencyAwareSpatialAttention via MFMA.
// R15: R14's rows-in-lanes structure + __launch_bounds__(512,8).
// Evidence (R7/R13/R14): launch_bounds' 2nd arg CAPS resident waves/EU —
// (512,4) => 42% occupancy; (512,8) => 84% (R13). R13 spilled only because
// the column structure needed 68 live VGPRs vs the 64 budget; R14's row
// structure sits at VGPR=56 and fits. Waves/CU is the one variable that has
// tracked BW across 15 rounds of this latency-bound staging kernel.
//   - lane (grp,i) = window row i of a channel pair; 5 float4 loads/channel
//   - sobel: (1,2,1) vertical via DPP wave_shr/shl, (-1,0,1) horizontal
//     in-register rolling window (fast path; general fallback kept)
//   - frq unpadded 289 rows + zero-row 289 (37.1 KB => 4 blocks/CU)
//   - conv 64->16 3x3: 9 offsets x 2 mfma_f32_16x16x32_bf16 (K=64)
//   - XCD-chunked block swizzle (bijective, 3600 = 8*450)

#define NT  512           // 8 waves
#define CH  (510 * 510)   // floats per channel plane

typedef __attribute__((ext_vector_type(8))) short bf16x8;
typedef __attribute__((ext_vector_type(4))) float f32x4;

// XOR swizzle: involution within each 128B frq row (row = pixel index).
__device__ __forceinline__ int swz(int off) {
    return off ^ (((off >> 7) & 7) << 4);
}

__device__ __forceinline__ unsigned short f2bf(float f) {
    union { float f; unsigned u; } v; v.f = f;
    unsigned u = v.u;
    unsigned r = u + 0x7fffu + ((u >> 16) & 1u);   // RNE
    return (unsigned short)(r >> 16);
}

// lane i <- lane i-1 (wave_shr:1), lane 0 <- 0
__device__ __forceinline__ float dpp_shr1(float v) {
    return __int_as_float(
        __builtin_amdgcn_update_dpp(0, __float_as_int(v), 0x138, 0xf, 0xf, true));
}
// lane i <- lane i+1 (wave_shl:1), lane 63 <- 0
__device__ __forceinline__ float dpp_shl1(float v) {
    return __int_as_float(
        __builtin_amdgcn_update_dpp(0, __float_as_int(v), 0x130, 0xf, 0xf, true));
}

// Pre-kernel: transpose+convert w1 [16][64][3][3] fp32 into A-fragment order.
// Fragment (dij, ks): lane l holds A[m = l&15][k = ks*32 + 8*(l>>4) + j], j=0..7.
__global__ void prep_w1(const float* __restrict__ w1, unsigned short* __restrict__ wt) {
    const int dij = blockIdx.x >> 1;
    const int ks  = blockIdx.x & 1;
    const int l   = threadIdx.x;           // 0..63
    const int m   = l & 15;
    const int kb  = ks * 32 + 8 * (l >> 4);
    bf16x8 v;
#pragma unroll
    for (int jj = 0; jj < 8; ++jj)
        v[jj] = (short)f2bf(w1[m * 576 + (kb + jj) * 9 + dij]);
    ((bf16x8*)wt)[blockIdx.x * 64 + l] = v;
}

__global__ __launch_bounds__(NT, 8)
void fasa_mfma(const float* __restrict__ x,
               const float* __restrict__ sobel_w,
               const unsigned short* __restrict__ wt,
               const float* __restrict__ b1,
               const float* __restrict__ w2,
               const float* __restrict__ b2,
               float* __restrict__ out)
{
    // frq: rows 0..288 = pixels (i*17+j), row 289 = shared zero row
    __shared__ __align__(16) char frq[290 * 128];      // 37120 B

    const int t    = threadIdx.x;
    const int lane = t & 63;
    const int wave = __builtin_amdgcn_readfirstlane(t >> 6);

    // XCD-chunked swizzle (bijective, 3600 = 8*450)
    const int bid = blockIdx.x;
    const int win = (bid & 7) * 450 + (bid >> 3);   // b*900 + wh*30 + ww
    const int b   = win / 900;
    const int rem = win % 900;
    const int h0  = (rem / 30) * 17;
    const int w0  = (rem % 30) * 17;

    // zero row 289 of frq (ordered by the pre-MFMA barrier)
    if (t < 8) *(f32x4*)(frq + 289 * 128 + t * 16) = (f32x4){0.f, 0.f, 0.f, 0.f};

    // sobel weights: all channels share one 3x3 (tiled in setup) -> scalar
    const float sw0 = sobel_w[0], sw1 = sobel_w[1], sw2 = sobel_w[2];
    const float sw3 = sobel_w[3], sw4 = sobel_w[4], sw5 = sobel_w[5];
    const float sw6 = sobel_w[6], sw7 = sobel_w[7], sw8 = sobel_w[8];
    // fast path: middle column zero, col0 = -col2 (true for Sobel)
    const bool fast = (sw1 == 0.f) && (sw4 == 0.f) && (sw7 == 0.f) &&
                      (sw0 == -sw2) && (sw3 == -sw5) && (sw6 == -sw8);

    const int i   = lane & 31;       // window ROW, active when i < 17
    const int grp = lane >> 5;       // which channel pair of this wave's two
    const bool iac = (i < 17);

    // row base (per-lane); inactive lanes never dereference (predicated)
    const float* xb = x + (size_t)b * 64 * CH + (size_t)(h0 + i) * 510 + w0;

    auto PROC = [&](int q) {
        const int pr = 2 * wave + grp + 16 * q;   // pair index 0..31
        const int cA = 2 * pr;                    // channels cA, cA+1
        f32x4 vA[5], vB[5];
#pragma unroll
        for (int k = 0; k < 5; ++k) {
            vA[k] = (f32x4){0.f, 0.f, 0.f, 0.f};
            vB[k] = (f32x4){0.f, 0.f, 0.f, 0.f};
        }
        if (iac) {
            const float* pA = xb + (size_t)cA * CH;
            const float* pB = pA + (size_t)CH;
#pragma unroll
            for (int k = 0; k < 4; ++k) {
                __builtin_memcpy(&vA[k], pA + 4 * k, 16);
                __builtin_memcpy(&vB[k], pB + 4 * k, 16);
            }
            // col 16 via overlapping load at col 13 (never out of bounds)
            __builtin_memcpy(&vA[4], pA + 13, 16);
            __builtin_memcpy(&vB[4], pB + 13, 16);
        }
        // col c -> vA[c>>2][c&3] (c<16), col 16 -> vA[4][3]; all const idx

        if (fast) {
            // s_j = sw2*row(i-1,j) + sw5*row(i,j) + sw8*row(i+1,j)  [DPP vertical]
            // out_j = s_{j+1} - s_{j-1}                             [in-lane]
            float sAp = 0.f, sBp = 0.f;      // s_{j-1}
            float sAc, sBc;                  // s_j
            {
                float rA = vA[0][0], rB = vB[0][0];
                sAc = fmaf(sw2, dpp_shr1(rA), fmaf(sw5, rA, sw8 * dpp_shl1(rA)));
                sBc = fmaf(sw2, dpp_shr1(rB), fmaf(sw5, rB, sw8 * dpp_shl1(rB)));
            }
#pragma unroll
            for (int j = 0; j < 17; ++j) {
                float sAn = 0.f, sBn = 0.f;  // s_{j+1}; col 17 pad -> 0
                if (j < 16) {
                    float rA = (j + 1 < 16) ? vA[(j + 1) >> 2][(j + 1) & 3] : vA[4][3];
                    float rB = (j + 1 < 16) ? vB[(j + 1) >> 2][(j + 1) & 3] : vB[4][3];
                    sAn = fmaf(sw2, dpp_shr1(rA), fmaf(sw5, rA, sw8 * dpp_shl1(rA)));
                    sBn = fmaf(sw2, dpp_shr1(rB), fmaf(sw5, rB, sw8 * dpp_shl1(rB)));
                }
                float oA = sAn - sAp;
                float oB = sBn - sBp;
                unsigned pkv;
                asm("v_cvt_pk_bf16_f32 %0, %1, %2" : "=v"(pkv) : "v"(oA), "v"(oB));
                if (iac)
                    *(unsigned*)(frq + swz((i * 17 + j) * 128 + pr * 4)) = pkv;
                sAp = sAc; sAc = sAn;
                sBp = sBc; sBc = sBn;
            }
        } else {
            // general: h^d_j = horizontal 3-tap with sobel row d on own row;
            // out_j = shr1(h0_j) + h1_j + shl1(h2_j)
            float rAm = 0.f, rBm = 0.f;
            float rAc = vA[0][0], rBc = vB[0][0];
#pragma unroll
            for (int j = 0; j < 17; ++j) {
                float rAn = 0.f, rBn = 0.f;
                if (j < 16) {
                    rAn = (j + 1 < 16) ? vA[(j + 1) >> 2][(j + 1) & 3] : vA[4][3];
                    rBn = (j + 1 < 16) ? vB[(j + 1) >> 2][(j + 1) & 3] : vB[4][3];
                }
                float hA0 = fmaf(sw0, rAm, fmaf(sw1, rAc, sw2 * rAn));
                float hA1 = fmaf(sw3, rAm, fmaf(sw4, rAc, sw5 * rAn));
                float hA2 = fmaf(sw6, rAm, fmaf(sw7, rAc, sw8 * rAn));
                float hB0 = fmaf(sw0, rBm, fmaf(sw1, rBc, sw2 * rBn));
                float hB1 = fmaf(sw3, rBm, fmaf(sw4, rBc, sw5 * rBn));
                float hB2 = fmaf(sw6, rBm, fmaf(sw7, rBc, sw8 * rBn));
                float oA = dpp_shr1(hA0) + hA1 + dpp_shl1(hA2);
                float oB = dpp_shr1(hB0) + hB1 + dpp_shl1(hB2);
                unsigned pkv;
                asm("v_cvt_pk_bf16_f32 %0, %1, %2" : "=v"(pkv) : "v"(oA), "v"(oB));
                if (iac)
                    *(unsigned*)(frq + swz((i * 17 + j) * 128 + pr * 4)) = pkv;
                rAm = rAc; rAc = rAn;
                rBm = rBc; rBc = rBn;
            }
        }
    };

    PROC(0);
    PROC(1);

    // ---- W fragments + epilogue constants ----
    bf16x8 wf[18];
#pragma unroll
    for (int k = 0; k < 18; ++k)
        wf[k] = ((const bf16x8*)wt)[k * 64 + lane];

    float b1v[4], w2v[4];
#pragma unroll
    for (int r = 0; r < 4; ++r) {
        int m = 4 * (lane >> 4) + r;
        b1v[r] = b1[m];
        w2v[r] = w2[m];
    }
    const float b2v = b2[0];

    __syncthreads();   // single barrier: frq complete across waves

    // ---- conv1 via MFMA: wave w handles pixel tiles {w, w+8, w+16} ----
    const int n   = lane & 15;          // pixel within tile (MFMA N)
    const int g16 = (lane >> 4) * 16;   // 8-channel chunk byte offset

#pragma unroll 1
    for (int nt = wave; nt < 19; nt += 8) {
        int p  = nt * 16 + n;
        int pv = p > 288 ? 288 : p;     // clamp dead lanes of last tile
        int pi = pv / 17, pj = pv - pi * 17;

        f32x4 acc = {0.f, 0.f, 0.f, 0.f};
#pragma unroll
        for (int d = 0; d < 9; ++d) {
            const int di = d / 3 - 1, dj = d % 3 - 1;      // compile-time
            bool ok = ((unsigned)(pi + di) < 17u) & ((unsigned)(pj + dj) < 17u);
            int row = ok ? (pv + di * 17 + dj) : 289;      // 289 = zero row
            int off = row * 128 + g16;
            bf16x8 bfA = *(const bf16x8*)(frq + swz(off));
            bf16x8 bfB = *(const bf16x8*)(frq + swz(off + 64));
            acc = __builtin_amdgcn_mfma_f32_16x16x32_bf16(wf[2 * d],     bfA, acc, 0, 0, 0);
            acc = __builtin_amdgcn_mfma_f32_16x16x32_bf16(wf[2 * d + 1], bfB, acc, 0, 0, 0);
        }

        float part = 0.f;
#pragma unroll
        for (int r = 0; r < 4; ++r)
            part = fmaf(w2v[r], fmaxf(acc[r] + b1v[r], 0.f), part);
        part += __shfl_xor(part, 16);
        part += __shfl_xor(part, 32);

        if (lane < 16 && p < 289) {
            float pre = part + b2v;
            float s = 1.f / (1.f + expf(-pre));
            s = fminf(fmaxf(s, 0.05f), 0.95f);
            out[((size_t)(b * 510 + h0 + pi)) * 510 + (w0 + pj)] = s;
        }
    }
}

extern "C" void kernel_launch(void* const* d_in, const int* in_sizes, int n_in,
                              void* d_out, int out_size, void* d_ws, size_t ws_size,
                              hipStream_t stream) {
    const float* x       = (const float*)d_in[0];
    const float* sobel_w = (const float*)d_in[1];
    const float* w1      = (const float*)d_in[2];
    const float* b1      = (const float*)d_in[3];
    const float* w2      = (const float*)d_in[4];
    const float* b2      = (const float*)d_in[5];
    float* out = (float*)d_out;
    unsigned short* wtab = (unsigned short*)d_ws;   // 18*64*16 = 18432 B

    prep_w1<<<dim3(18), dim3(64), 0, stream>>>(w1, wtab);
    fasa_mfma<<<dim3(3600), dim3(NT), 0, stream>>>(x, sobel_w, wtab, b1, w2, b2, out);
}

// Round 16
// 112.061 us; speedup vs baseline: 2.4120x; 2.4120x over previous
//
#include <hip/hip_runtime.h>

// FrequencyAwareSpatialAttention via MFMA.
// R16: true 8-waves/EU occupancy. Evidence chain: (512,8) budget = 64 unified
// regs/wave; wf[18] W-fragments = 72 regs made that impossible (R13/R15
// spill signature: VGPR=32 + FETCH x4). Fix: stream W-fragments from the
// 18KB global wtab INSIDE the MFMA loop (L1/L2-hot, shared by all waves),
// MFMA d-loop unroll-1 over rows to cap liveness. Staging = R14's validated
// rows-in-lanes (lane = window row, 5 float4 loads/channel, DPP vertical
// smoothing + in-register horizontal difference).
//   - frq unpadded 289 rows + zero-row 289 (37.1 KB LDS => 4 blocks/CU,
//     4 x 512 threads = 2048 = CU thread cap => 32 waves/CU target)
//   - conv 64->16 3x3: 9 offsets x 2 mfma_f32_16x16x32_bf16 (K=64)
//   - XCD-chunked block swizzle (bijective, 3600 = 8*450)

#define NT  512           // 8 waves
#define CH  (510 * 510)   // floats per channel plane

typedef __attribute__((ext_vector_type(8))) short bf16x8;
typedef __attribute__((ext_vector_type(4))) float f32x4;

// XOR swizzle: involution within each 128B frq row (row = pixel index).
__device__ __forceinline__ int swz(int off) {
    return off ^ (((off >> 7) & 7) << 4);
}

__device__ __forceinline__ unsigned short f2bf(float f) {
    union { float f; unsigned u; } v; v.f = f;
    unsigned u = v.u;
    unsigned r = u + 0x7fffu + ((u >> 16) & 1u);   // RNE
    return (unsigned short)(r >> 16);
}

// lane i <- lane i-1 (wave_shr:1), lane 0 <- 0
__device__ __forceinline__ float dpp_shr1(float v) {
    return __int_as_float(
        __builtin_amdgcn_update_dpp(0, __float_as_int(v), 0x138, 0xf, 0xf, true));
}
// lane i <- lane i+1 (wave_shl:1), lane 63 <- 0
__device__ __forceinline__ float dpp_shl1(float v) {
    return __int_as_float(
        __builtin_amdgcn_update_dpp(0, __float_as_int(v), 0x130, 0xf, 0xf, true));
}

// Pre-kernel: transpose+convert w1 [16][64][3][3] fp32 into A-fragment order.
// Fragment (dij, ks): lane l holds A[m = l&15][k = ks*32 + 8*(l>>4) + j], j=0..7.
__global__ void prep_w1(const float* __restrict__ w1, unsigned short* __restrict__ wt) {
    const int dij = blockIdx.x >> 1;
    const int ks  = blockIdx.x & 1;
    const int l   = threadIdx.x;           // 0..63
    const int m   = l & 15;
    const int kb  = ks * 32 + 8 * (l >> 4);
    bf16x8 v;
#pragma unroll
    for (int jj = 0; jj < 8; ++jj)
        v[jj] = (short)f2bf(w1[m * 576 + (kb + jj) * 9 + dij]);
    ((bf16x8*)wt)[blockIdx.x * 64 + l] = v;
}

__global__ __launch_bounds__(NT, 8)
void fasa_mfma(const float* __restrict__ x,
               const float* __restrict__ sobel_w,
               const unsigned short* __restrict__ wt,
               const float* __restrict__ b1,
               const float* __restrict__ w2,
               const float* __restrict__ b2,
               float* __restrict__ out)
{
    // frq: rows 0..288 = pixels (i*17+j), row 289 = shared zero row
    __shared__ __align__(16) char frq[290 * 128];      // 37120 B

    const int t    = threadIdx.x;
    const int lane = t & 63;
    const int wave = __builtin_amdgcn_readfirstlane(t >> 6);

    // XCD-chunked swizzle (bijective, 3600 = 8*450)
    const int bid = blockIdx.x;
    const int win = (bid & 7) * 450 + (bid >> 3);   // b*900 + wh*30 + ww
    const int b   = win / 900;
    const int rem = win % 900;
    const int h0  = (rem / 30) * 17;
    const int w0  = (rem % 30) * 17;

    // zero row 289 of frq (ordered by the pre-MFMA barrier)
    if (t < 8) *(f32x4*)(frq + 289 * 128 + t * 16) = (f32x4){0.f, 0.f, 0.f, 0.f};

    // sobel weights: all channels share one 3x3 (tiled in setup) -> SGPRs
    const float sw0 = sobel_w[0], sw1 = sobel_w[1], sw2 = sobel_w[2];
    const float sw3 = sobel_w[3], sw4 = sobel_w[4], sw5 = sobel_w[5];
    const float sw6 = sobel_w[6], sw7 = sobel_w[7], sw8 = sobel_w[8];
    // fast path: middle column zero, col0 = -col2 (true for Sobel)
    const bool fast = (sw1 == 0.f) && (sw4 == 0.f) && (sw7 == 0.f) &&
                      (sw0 == -sw2) && (sw3 == -sw5) && (sw6 == -sw8);

    const int i   = lane & 31;       // window ROW, active when i < 17
    const int grp = lane >> 5;       // which channel pair of this wave's two
    const bool iac = (i < 17);

    // row base (per-lane); inactive lanes never dereference (predicated)
    const float* xb = x + (size_t)b * 64 * CH + (size_t)(h0 + i) * 510 + w0;

    auto PROC = [&](int q) {
        const int pr = 2 * wave + grp + 16 * q;   // pair index 0..31
        const int cA = 2 * pr;                    // channels cA, cA+1
        f32x4 vA[5], vB[5];
#pragma unroll
        for (int k = 0; k < 5; ++k) {
            vA[k] = (f32x4){0.f, 0.f, 0.f, 0.f};
            vB[k] = (f32x4){0.f, 0.f, 0.f, 0.f};
        }
        if (iac) {
            const float* pA = xb + (size_t)cA * CH;
            const float* pB = pA + (size_t)CH;
#pragma unroll
            for (int k = 0; k < 4; ++k) {
                __builtin_memcpy(&vA[k], pA + 4 * k, 16);
                __builtin_memcpy(&vB[k], pB + 4 * k, 16);
            }
            // col 16 via overlapping load at col 13 (never out of bounds)
            __builtin_memcpy(&vA[4], pA + 13, 16);
            __builtin_memcpy(&vB[4], pB + 13, 16);
        }
        // col c -> vA[c>>2][c&3] (c<16), col 16 -> vA[4][3]; all const idx

        if (fast) {
            // s_j = sw2*row(i-1,j) + sw5*row(i,j) + sw8*row(i+1,j)  [DPP vertical]
            // out_j = s_{j+1} - s_{j-1}                             [in-lane]
            float sAp = 0.f, sBp = 0.f;      // s_{j-1}
            float sAc, sBc;                  // s_j
            {
                float rA = vA[0][0], rB = vB[0][0];
                sAc = fmaf(sw2, dpp_shr1(rA), fmaf(sw5, rA, sw8 * dpp_shl1(rA)));
                sBc = fmaf(sw2, dpp_shr1(rB), fmaf(sw5, rB, sw8 * dpp_shl1(rB)));
            }
#pragma unroll
            for (int j = 0; j < 17; ++j) {
                float sAn = 0.f, sBn = 0.f;  // s_{j+1}; col 17 pad -> 0
                if (j < 16) {
                    float rA = (j + 1 < 16) ? vA[(j + 1) >> 2][(j + 1) & 3] : vA[4][3];
                    float rB = (j + 1 < 16) ? vB[(j + 1) >> 2][(j + 1) & 3] : vB[4][3];
                    sAn = fmaf(sw2, dpp_shr1(rA), fmaf(sw5, rA, sw8 * dpp_shl1(rA)));
                    sBn = fmaf(sw2, dpp_shr1(rB), fmaf(sw5, rB, sw8 * dpp_shl1(rB)));
                }
                float oA = sAn - sAp;
                float oB = sBn - sBp;
                unsigned pkv;
                asm("v_cvt_pk_bf16_f32 %0, %1, %2" : "=v"(pkv) : "v"(oA), "v"(oB));
                if (iac)
                    *(unsigned*)(frq + swz((i * 17 + j) * 128 + pr * 4)) = pkv;
                sAp = sAc; sAc = sAn;
                sBp = sBc; sBc = sBn;
            }
        } else {
            // general: h^d_j = horizontal 3-tap with sobel row d on own row;
            // out_j = shr1(h0_j) + h1_j + shl1(h2_j)
            float rAm = 0.f, rBm = 0.f;
            float rAc = vA[0][0], rBc = vB[0][0];
#pragma unroll
            for (int j = 0; j < 17; ++j) {
                float rAn = 0.f, rBn = 0.f;
                if (j < 16) {
                    rAn = (j + 1 < 16) ? vA[(j + 1) >> 2][(j + 1) & 3] : vA[4][3];
                    rBn = (j + 1 < 16) ? vB[(j + 1) >> 2][(j + 1) & 3] : vB[4][3];
                }
                float hA0 = fmaf(sw0, rAm, fmaf(sw1, rAc, sw2 * rAn));
                float hA1 = fmaf(sw3, rAm, fmaf(sw4, rAc, sw5 * rAn));
                float hA2 = fmaf(sw6, rAm, fmaf(sw7, rAc, sw8 * rAn));
                float hB0 = fmaf(sw0, rBm, fmaf(sw1, rBc, sw2 * rBn));
                float hB1 = fmaf(sw3, rBm, fmaf(sw4, rBc, sw5 * rBn));
                float hB2 = fmaf(sw6, rBm, fmaf(sw7, rBc, sw8 * rBn));
                float oA = dpp_shr1(hA0) + hA1 + dpp_shl1(hA2);
                float oB = dpp_shr1(hB0) + hB1 + dpp_shl1(hB2);
                unsigned pkv;
                asm("v_cvt_pk_bf16_f32 %0, %1, %2" : "=v"(pkv) : "v"(oA), "v"(oB));
                if (iac)
                    *(unsigned*)(frq + swz((i * 17 + j) * 128 + pr * 4)) = pkv;
                rAm = rAc; rAc = rAn;
                rBm = rBc; rBc = rBn;
            }
        }
    };

    PROC(0);
    PROC(1);

    // ---- epilogue constants only (W fragments now streamed from global) ----
    float b1v[4], w2v[4];
#pragma unroll
    for (int r = 0; r < 4; ++r) {
        int m = 4 * (lane >> 4) + r;
        b1v[r] = b1[m];
        w2v[r] = w2[m];
    }
    const float b2v = b2[0];

    __syncthreads();   // single barrier: frq complete across waves

    // ---- conv1 via MFMA: wave w handles pixel tiles {w, w+8, w+16} ----
    // W fragments read per-use from the 18KB wtab (L1/L2-hot: shared by
    // every wave on the chip). Liveness ~30 regs => fits the 64-reg budget.
    const int n   = lane & 15;          // pixel within tile (MFMA N)
    const int g16 = (lane >> 4) * 16;   // 8-channel chunk byte offset
    const bf16x8* wtv = (const bf16x8*)wt;   // element (dij*2+ks)*64 + lane

#pragma unroll 1
    for (int nt = wave; nt < 19; nt += 8) {
        int p  = nt * 16 + n;
        int pv = p > 288 ? 288 : p;     // clamp dead lanes of last tile
        int pi = pv / 17, pj = pv - pi * 17;

        f32x4 acc = {0.f, 0.f, 0.f, 0.f};
#pragma unroll 1
        for (int dd = 0; dd < 3; ++dd) {           // kernel row (di = dd-1)
            const bool okr = ((unsigned)(pi + dd - 1) < 17u);
            const int rb = pv + (dd - 1) * 17;
            const bf16x8* wrow = wtv + (size_t)(3 * dd) * 128 + lane;
#pragma unroll
            for (int dj = 0; dj < 3; ++dj) {       // kernel col (compile-time)
                bool ok = okr & ((unsigned)(pj + dj - 1) < 17u);
                int row = ok ? (rb + dj - 1) : 289;      // 289 = zero row
                int off = row * 128 + g16;
                bf16x8 bfA = *(const bf16x8*)(frq + swz(off));
                bf16x8 bfB = *(const bf16x8*)(frq + swz(off + 64));
                bf16x8 wfA = wrow[dj * 128];
                bf16x8 wfB = wrow[dj * 128 + 64];
                acc = __builtin_amdgcn_mfma_f32_16x16x32_bf16(wfA, bfA, acc, 0, 0, 0);
                acc = __builtin_amdgcn_mfma_f32_16x16x32_bf16(wfB, bfB, acc, 0, 0, 0);
            }
        }

        float part = 0.f;
#pragma unroll
        for (int r = 0; r < 4; ++r)
            part = fmaf(w2v[r], fmaxf(acc[r] + b1v[r], 0.f), part);
        part += __shfl_xor(part, 16);
        part += __shfl_xor(part, 32);

        if (lane < 16 && p < 289) {
            float pre = part + b2v;
            float s = 1.f / (1.f + expf(-pre));
            s = fminf(fmaxf(s, 0.05f), 0.95f);
            out[((size_t)(b * 510 + h0 + pi)) * 510 + (w0 + pj)] = s;
        }
    }
}

extern "C" void kernel_launch(void* const* d_in, const int* in_sizes, int n_in,
                              void* d_out, int out_size, void* d_ws, size_t ws_size,
                              hipStream_t stream) {
    const float* x       = (const float*)d_in[0];
    const float* sobel_w = (const float*)d_in[1];
    const float* w1      = (const float*)d_in[2];
    const float* b1      = (const float*)d_in[3];
    const float* w2      = (const float*)d_in[4];
    const float* b2      = (const float*)d_in[5];
    float* out = (float*)d_out;
    unsigned short* wtab = (unsigned short*)d_ws;   // 18*64*16 = 18432 B

    prep_w1<<<dim3(18), dim3(64), 0, stream>>>(w1, wtab);
    fasa_mfma<<<dim3(3600), dim3(NT), 0, stream>>>(x, sobel_w, wtab, b1, w2, b2, out);
}

// Round 17
// 86.472 us; speedup vs baseline: 3.1258x; 1.2959x over previous
//
#include <hip/hip_runtime.h>

// FrequencyAwareSpatialAttention via MFMA.
// R17: R10 baseline (best, 90.5us) + SEPARABLE fast sobel.
// Across R7-R16: cold time pinned at 148-185us for every memory-side
// configuration (waves 13<->30/CU, depth 1<->8, scalar/vector/DMA staging).
// The invariant large cost is ~50us of VALU busy-time; sobel is separable
// (cols (-1,0,1) x rows (1,2,1)) => h_i = sw2*x_{i-1}+sw5*x_i+sw8*x_{i+1}
// (3 packed ops/pair), o = shl1(h)-shr1(h) (4 DPP + 1 pk-sub): ~10 vs ~17
// wave-inst per (elem,pair), -41% staging VALU. General fallback kept.
// Staging: inline-asm global_load clusters + counted vmcnt (R10-proven).
// conv 64->16 3x3: 9 offsets x 2 mfma_f32_16x16x32_bf16 (K=64) on swizzled
// bf16 frq; +b1, relu, 1x1 conv +b2, sigmoid, clip. XCD-chunked swizzle.

#define WSZ 17
#define PS  19            // padded 17+2
#define PSS (PS * PS)     // 361
#define NT  512           // 8 waves
#define CH  (510 * 510)   // floats per channel plane

typedef __attribute__((ext_vector_type(8))) short bf16x8;
typedef __attribute__((ext_vector_type(4))) float f32x4;
typedef __attribute__((ext_vector_type(2))) float f32x2;

// XOR swizzle: involution within each 128B frq row (row = padded pixel).
__device__ __forceinline__ int swz(int off) {
    return off ^ (((off >> 7) & 7) << 4);
}

__device__ __forceinline__ unsigned short f2bf(float f) {
    union { float f; unsigned u; } v; v.f = f;
    unsigned u = v.u;
    unsigned r = u + 0x7fffu + ((u >> 16) & 1u);   // RNE
    return (unsigned short)(r >> 16);
}

// lane i <- lane i-1 (wave_shr:1), lane 0 <- 0
__device__ __forceinline__ float dpp_shr1(float v) {
    return __int_as_float(
        __builtin_amdgcn_update_dpp(0, __float_as_int(v), 0x138, 0xf, 0xf, true));
}
// lane i <- lane i+1 (wave_shl:1), lane 63 <- 0
__device__ __forceinline__ float dpp_shl1(float v) {
    return __int_as_float(
        __builtin_amdgcn_update_dpp(0, __float_as_int(v), 0x130, 0xf, 0xf, true));
}

// 8 forced-depth loads: rows 2k,2k+1 at voff k via offset:0/2040 immediates.
#define GLD8(d0,d1,d2,d3,d4,d5,d6,d7, o0,o1,o2,o3, sp)      \
    asm volatile(                                            \
        "global_load_dword %0, %8, %12\n\t"                  \
        "global_load_dword %1, %8, %12 offset:2040\n\t"      \
        "global_load_dword %2, %9, %12\n\t"                  \
        "global_load_dword %3, %9, %12 offset:2040\n\t"      \
        "global_load_dword %4, %10, %12\n\t"                 \
        "global_load_dword %5, %10, %12 offset:2040\n\t"     \
        "global_load_dword %6, %11, %12\n\t"                 \
        "global_load_dword %7, %11, %12 offset:2040\n\t"     \
        : "+v"(d0),"+v"(d1),"+v"(d2),"+v"(d3),               \
          "+v"(d4),"+v"(d5),"+v"(d6),"+v"(d7)                \
        : "v"(o0),"v"(o1),"v"(o2),"v"(o3),"s"(sp))

// 9 loads: rows 8..15 (pairs) + row 16.
#define GLD9(d0,d1,d2,d3,d4,d5,d6,d7,d8, o0,o1,o2,o3,o4, sp) \
    asm volatile(                                            \
        "global_load_dword %0, %9, %14\n\t"                  \
        "global_load_dword %1, %9, %14 offset:2040\n\t"      \
        "global_load_dword %2, %10, %14\n\t"                 \
        "global_load_dword %3, %10, %14 offset:2040\n\t"     \
        "global_load_dword %4, %11, %14\n\t"                 \
        "global_load_dword %5, %11, %14 offset:2040\n\t"     \
        "global_load_dword %6, %12, %14\n\t"                 \
        "global_load_dword %7, %12, %14 offset:2040\n\t"     \
        "global_load_dword %8, %13, %14\n\t"                 \
        : "+v"(d0),"+v"(d1),"+v"(d2),"+v"(d3),"+v"(d4),      \
          "+v"(d5),"+v"(d6),"+v"(d7),"+v"(d8)                \
        : "v"(o0),"v"(o1),"v"(o2),"v"(o3),"v"(o4),"s"(sp))

// Pre-kernel: transpose+convert w1 [16][64][3][3] fp32 into A-fragment order.
// Fragment (dij, ks): lane l holds A[m = l&15][k = ks*32 + 8*(l>>4) + j], j=0..7.
__global__ void prep_w1(const float* __restrict__ w1, unsigned short* __restrict__ wt) {
    const int dij = blockIdx.x >> 1;
    const int ks  = blockIdx.x & 1;
    const int l   = threadIdx.x;           // 0..63
    const int m   = l & 15;
    const int kb  = ks * 32 + 8 * (l >> 4);
    bf16x8 v;
#pragma unroll
    for (int jj = 0; jj < 8; ++jj)
        v[jj] = (short)f2bf(w1[m * 576 + (kb + jj) * 9 + dij]);
    ((bf16x8*)wt)[blockIdx.x * 64 + l] = v;
}

__global__ __launch_bounds__(NT, 4)
void fasa_mfma(const float* __restrict__ x,
               const float* __restrict__ sobel_w,
               const unsigned short* __restrict__ wt,
               const float* __restrict__ b1,
               const float* __restrict__ w2,
               const float* __restrict__ b2,
               float* __restrict__ out)
{
    __shared__ __align__(16) char frq[PSS * 128];   // 46.2 KB, [pp][c] bf16 swizzled

    const int t    = threadIdx.x;
    const int lane = t & 63;
    const int wave = __builtin_amdgcn_readfirstlane(t >> 6);

    // XCD-chunked swizzle (bijective, 3600 = 8*450)
    const int bid = blockIdx.x;
    const int win = (bid & 7) * 450 + (bid >> 3);   // b*900 + wh*30 + ww
    const int b   = win / 900;
    const int rem = win % 900;
    const int h0  = (rem / 30) * WSZ;
    const int w0  = (rem % 30) * WSZ;

    // ---- zero the 72 border rows of frq (interior rows all get written) ----
    for (int u = t; u < 72 * 8; u += NT) {
        int r = u >> 3, k = u & 7;
        int row;
        if      (r < 19) row = r;                   // pi == 0
        else if (r < 38) row = 342 + (r - 19);      // pi == 18
        else if (r < 55) row = (r - 37) * PS;       // pj == 0, pi 1..17
        else             row = (r - 54) * PS + 18;  // pj == 18, pi 1..17
        *(f32x4*)(frq + row * 128 + k * 16) = (f32x4){0.f, 0.f, 0.f, 0.f};
    }

    // ---- sobel weights: ALL channels share one 3x3 (tiled in setup) ----
    const float sw0 = sobel_w[0], sw1 = sobel_w[1], sw2 = sobel_w[2];
    const float sw3 = sobel_w[3], sw4 = sobel_w[4], sw5 = sobel_w[5];
    const float sw6 = sobel_w[6], sw7 = sobel_w[7], sw8 = sobel_w[8];
    // separable fast path: middle column zero, col0 = -col2 (true for Sobel)
    const bool fast = (sw1 == 0.f) && (sw4 == 0.f) && (sw7 == 0.f) &&
                      (sw0 == -sw2) && (sw3 == -sw5) && (sw6 == -sw8);

    // ---- staging: lane = (grp, j); pair = 2*wave + grp + 16*q, q = 0,1 ----
    const int j   = lane & 31;       // column, active when j < 17
    const int grp = lane >> 5;       // which pair of this wave's two
    const bool jac = (j < 17);

    // wave-uniform bases: channel 4*wave, then q/y offsets folded into saddr
    const float* sp00 = x + ((size_t)(b * 64 + 4 * wave)) * CH
                          + (size_t)h0 * 510 + w0;
    const float* sp01 = sp00 + (size_t)CH;        // +1 channel (y of pair)
    const float* sp10 = sp00 + (size_t)32 * CH;   // q=1
    const float* sp11 = sp10 + (size_t)CH;

    // per-lane voffsets: channel-pair offset + column + row pairs (4080*k)
    const unsigned v0 = (unsigned)((grp * 2 * CH + j) * 4);
    const unsigned vk0 = v0,           vk1 = v0 + 4080u,  vk2 = v0 + 8160u;
    const unsigned vk3 = v0 + 12240u,  vk4 = v0 + 16320u, vk5 = v0 + 20400u;
    const unsigned vk6 = v0 + 24480u,  vk7 = v0 + 28560u, vk8 = v0 + 32640u;

    // data regs, pre-zeroed at full exec so inactive lanes (j>=17) keep the
    // zero columns the DPP edge handling relies on (lanes 17/31/49/63).
    float xA[17], yA[17], xB[17], yB[17];
#pragma unroll
    for (int i = 0; i < 17; ++i) { xA[i] = 0.f; yA[i] = 0.f; xB[i] = 0.f; yB[i] = 0.f; }

    if (jac) {
        GLD8(xA[0],xA[1],xA[2],xA[3],xA[4],xA[5],xA[6],xA[7], vk0,vk1,vk2,vk3, sp00);
        GLD9(xA[8],xA[9],xA[10],xA[11],xA[12],xA[13],xA[14],xA[15],xA[16],
             vk4,vk5,vk6,vk7,vk8, sp00);
        GLD8(yA[0],yA[1],yA[2],yA[3],yA[4],yA[5],yA[6],yA[7], vk0,vk1,vk2,vk3, sp01);
        GLD9(yA[8],yA[9],yA[10],yA[11],yA[12],yA[13],yA[14],yA[15],yA[16],
             vk4,vk5,vk6,vk7,vk8, sp01);
        GLD8(xB[0],xB[1],xB[2],xB[3],xB[4],xB[5],xB[6],xB[7], vk0,vk1,vk2,vk3, sp10);
        GLD9(xB[8],xB[9],xB[10],xB[11],xB[12],xB[13],xB[14],xB[15],xB[16],
             vk4,vk5,vk6,vk7,vk8, sp10);
        GLD8(yB[0],yB[1],yB[2],yB[3],yB[4],yB[5],yB[6],yB[7], vk0,vk1,vk2,vk3, sp11);
        GLD9(yB[8],yB[9],yB[10],yB[11],yB[12],yB[13],yB[14],yB[15],yB[16],
             vk4,vk5,vk6,vk7,vk8, sp11);
    }

    auto DOSOBEL = [&](const float* xr, const float* yr, int q) {
        const int pr = 2 * wave + grp + 16 * q;       // pair index 0..31
        const int pairOff = pr * 4;                   // pair byte offset in frq row
        if (fast) {
            // separable: h_i = sw2*x_{i-1} + sw5*x_i + sw8*x_{i+1} (in-lane),
            // o_i(j) = h_i(j+1) - h_i(j-1) via DPP. Zero cols at j>=17 pad.
#pragma unroll
            for (int i = 0; i < 17; ++i) {
                f32x2 top = { (i > 0  ? xr[i - 1] : 0.f), (i > 0  ? yr[i - 1] : 0.f) };
                f32x2 mid = { xr[i],                       yr[i] };
                f32x2 bot = { (i < 16 ? xr[i + 1] : 0.f), (i < 16 ? yr[i + 1] : 0.f) };
                f32x2 h = sw2 * top + sw5 * mid + sw8 * bot;   // 3 packed ops
                f32x2 o;
                o.x = dpp_shl1(h.x) - dpp_shr1(h.x);
                o.y = dpp_shl1(h.y) - dpp_shr1(h.y);
                unsigned pkv;
                asm("v_cvt_pk_bf16_f32 %0, %1, %2" : "=v"(pkv) : "v"(o.x), "v"(o.y));
                if (jac)
                    *(unsigned*)(frq + swz(((i + 1) * PS + (j + 1)) * 128 + pairOff)) = pkv;
            }
        } else {
            // general 9-tap (R10-validated)
#pragma unroll
            for (int i = 0; i < 17; ++i) {
                f32x2 top = { (i > 0  ? xr[i - 1] : 0.f), (i > 0  ? yr[i - 1] : 0.f) };
                f32x2 mid = { xr[i],                       yr[i] };
                f32x2 bot = { (i < 16 ? xr[i + 1] : 0.f), (i < 16 ? yr[i + 1] : 0.f) };
                f32x2 p0 = sw0 * top + sw3 * mid + sw6 * bot;
                f32x2 p1 = sw1 * top + sw4 * mid + sw7 * bot;
                f32x2 p2 = sw2 * top + sw5 * mid + sw8 * bot;
                f32x2 o;
                o.x = p1.x + dpp_shr1(p0.x) + dpp_shl1(p2.x);
                o.y = p1.y + dpp_shr1(p0.y) + dpp_shl1(p2.y);
                unsigned pkv;
                asm("v_cvt_pk_bf16_f32 %0, %1, %2" : "=v"(pkv) : "v"(o.x), "v"(o.y));
                if (jac)
                    *(unsigned*)(frq + swz(((i + 1) * PS + (j + 1)) * 128 + pairOff)) = pkv;
            }
        }
    };

    // A ready (B's 34 still in flight under sobel A), then drain for B.
    asm volatile("s_waitcnt vmcnt(34)" ::: "memory");
    __builtin_amdgcn_sched_barrier(0);
    DOSOBEL(xA, yA, 0);
    asm volatile("s_waitcnt vmcnt(0)" ::: "memory");
    __builtin_amdgcn_sched_barrier(0);
    DOSOBEL(xB, yB, 1);

    // ---- W fragments + epilogue constants: issue before barrier ----
    bf16x8 wf[18];
#pragma unroll
    for (int i = 0; i < 18; ++i)
        wf[i] = ((const bf16x8*)wt)[i * 64 + lane];

    float b1v[4], w2v[4];
#pragma unroll
    for (int r = 0; r < 4; ++r) {
        int m = 4 * (lane >> 4) + r;
        b1v[r] = b1[m];
        w2v[r] = w2[m];
    }
    const float b2v = b2[0];

    __syncthreads();

    // ---- conv1 via MFMA: wave w handles pixel tiles {w, w+8, w+16} ----
    const int n   = lane & 15;          // pixel within tile (MFMA N)
    const int g16 = (lane >> 4) * 16;   // 8-channel chunk byte offset
    const int DOFF[9] = {0, 1, 2, PS, PS + 1, PS + 2, 2 * PS, 2 * PS + 1, 2 * PS + 2};

#pragma unroll 1
    for (int nt = wave; nt < 19; nt += 8) {
        int p  = nt * 16 + n;
        int pv = p > 288 ? 288 : p;     // clamp dead lanes of last tile
        int pi = pv / 17, pj = pv - pi * 17;
        int base = (pi * PS + pj) * 128 + g16;

        f32x4 acc = {0.f, 0.f, 0.f, 0.f};
#pragma unroll
        for (int d = 0; d < 9; ++d) {
            int off = base + DOFF[d] * 128;
            bf16x8 bfA = *(const bf16x8*)(frq + swz(off));
            bf16x8 bfB = *(const bf16x8*)(frq + swz(off + 64));
            acc = __builtin_amdgcn_mfma_f32_16x16x32_bf16(wf[2 * d],     bfA, acc, 0, 0, 0);
            acc = __builtin_amdgcn_mfma_f32_16x16x32_bf16(wf[2 * d + 1], bfB, acc, 0, 0, 0);
        }

        float part = 0.f;
#pragma unroll
        for (int r = 0; r < 4; ++r)
            part = fmaf(w2v[r], fmaxf(acc[r] + b1v[r], 0.f), part);
        part += __shfl_xor(part, 16);
        part += __shfl_xor(part, 32);

        if (lane < 16 && p < 289) {
            float pre = part + b2v;
            float s = 1.f / (1.f + expf(-pre));
            s = fminf(fmaxf(s, 0.05f), 0.95f);
            out[((size_t)(b * 510 + h0 + pi)) * 510 + (w0 + pj)] = s;
        }
    }
}

extern "C" void kernel_launch(void* const* d_in, const int* in_sizes, int n_in,
                              void* d_out, int out_size, void* d_ws, size_t ws_size,
                              hipStream_t stream) {
    const float* x       = (const float*)d_in[0];
    const float* sobel_w = (const float*)d_in[1];
    const float* w1      = (const float*)d_in[2];
    const float* b1      = (const float*)d_in[3];
    const float* w2      = (const float*)d_in[4];
    const float* b2      = (const float*)d_in[5];
    float* out = (float*)d_out;
    unsigned short* wtab = (unsigned short*)d_ws;   // 18*64*16 = 18432 B

    prep_w1<<<dim3(18), dim3(64), 0, stream>>>(w1, wtab);
    fasa_mfma<<<dim3(3600), dim3(NT), 0, stream>>>(x, sobel_w, wtab, b1, w2, b2, out);
}

// Round 19
// 84.725 us; speedup vs baseline: 3.1902x; 1.0206x over previous
//
#include <hip/hip_runtime.h>

// FrequencyAwareSpatialAttention via MFMA.
// R19: R18 (f16 packed sobel + f16 MFMA) with the cvt_pkrtz type fixed —
// the builtin returns __fp16x2; bit-cast to our _Float16x2 via memcpy.
// v_pk_*_f16 handles both channels of a pair in ONE 32-bit reg: the
// horizontal diff drops from 4 DPP + 2 subs (f32x2) to 2 DPP + 1 pk-sub,
// and the explicit bf16 pack disappears (already packed). ~-27% of the
// dominant staging-VALU block. f16 (10 mantissa bits) is MORE precise than
// bf16 (7): absmax should drop ~4x. MFMA 16x16x32_f16 = same shape/rate.
// All else identical to R17 (86.5us): asm GLD clusters + counted vmcnt,
// swizzled padded frq, XCD-chunked swizzle, separable-sobel fast path.

#define WSZ 17
#define PS  19            // padded 17+2
#define PSS (PS * PS)     // 361
#define NT  512           // 8 waves
#define CH  (510 * 510)   // floats per channel plane

typedef __attribute__((ext_vector_type(8))) _Float16 f16x8;
typedef __attribute__((ext_vector_type(2))) _Float16 f16x2;
typedef __attribute__((ext_vector_type(4))) float f32x4;
typedef __attribute__((ext_vector_type(2))) float f32x2;

// XOR swizzle: involution within each 128B frq row (row = padded pixel).
__device__ __forceinline__ int swz(int off) {
    return off ^ (((off >> 7) & 7) << 4);
}

__device__ __forceinline__ unsigned short f2h(float f) {
    _Float16 h = (_Float16)f;                 // RNE
    unsigned short u;
    __builtin_memcpy(&u, &h, 2);
    return u;
}

// v_cvt_pkrtz_f16_f32: pack two f32 -> one reg of 2 halves (bit-cast type)
__device__ __forceinline__ f16x2 pkrtz(float a, float b) {
    auto r = __builtin_amdgcn_cvt_pkrtz(a, b);
    f16x2 o;
    __builtin_memcpy(&o, &r, 4);
    return o;
}

// lane i <- lane i-1 (wave_shr:1), lane 0 <- 0
__device__ __forceinline__ int dpp_shr1_i(int v) {
    return __builtin_amdgcn_update_dpp(0, v, 0x138, 0xf, 0xf, true);
}
// lane i <- lane i+1 (wave_shl:1), lane 63 <- 0
__device__ __forceinline__ int dpp_shl1_i(int v) {
    return __builtin_amdgcn_update_dpp(0, v, 0x130, 0xf, 0xf, true);
}
__device__ __forceinline__ float dpp_shr1(float v) {
    return __int_as_float(dpp_shr1_i(__float_as_int(v)));
}
__device__ __forceinline__ float dpp_shl1(float v) {
    return __int_as_float(dpp_shl1_i(__float_as_int(v)));
}

// 8 forced-depth loads: rows 2k,2k+1 at voff k via offset:0/2040 immediates.
#define GLD8(d0,d1,d2,d3,d4,d5,d6,d7, o0,o1,o2,o3, sp)      \
    asm volatile(                                            \
        "global_load_dword %0, %8, %12\n\t"                  \
        "global_load_dword %1, %8, %12 offset:2040\n\t"      \
        "global_load_dword %2, %9, %12\n\t"                  \
        "global_load_dword %3, %9, %12 offset:2040\n\t"      \
        "global_load_dword %4, %10, %12\n\t"                 \
        "global_load_dword %5, %10, %12 offset:2040\n\t"     \
        "global_load_dword %6, %11, %12\n\t"                 \
        "global_load_dword %7, %11, %12 offset:2040\n\t"     \
        : "+v"(d0),"+v"(d1),"+v"(d2),"+v"(d3),               \
          "+v"(d4),"+v"(d5),"+v"(d6),"+v"(d7)                \
        : "v"(o0),"v"(o1),"v"(o2),"v"(o3),"s"(sp))

// 9 loads: rows 8..15 (pairs) + row 16.
#define GLD9(d0,d1,d2,d3,d4,d5,d6,d7,d8, o0,o1,o2,o3,o4, sp) \
    asm volatile(                                            \
        "global_load_dword %0, %9, %14\n\t"                  \
        "global_load_dword %1, %9, %14 offset:2040\n\t"      \
        "global_load_dword %2, %10, %14\n\t"                 \
        "global_load_dword %3, %10, %14 offset:2040\n\t"     \
        "global_load_dword %4, %11, %14\n\t"                 \
        "global_load_dword %5, %11, %14 offset:2040\n\t"     \
        "global_load_dword %6, %12, %14\n\t"                 \
        "global_load_dword %7, %12, %14 offset:2040\n\t"     \
        "global_load_dword %8, %13, %14\n\t"                 \
        : "+v"(d0),"+v"(d1),"+v"(d2),"+v"(d3),"+v"(d4),      \
          "+v"(d5),"+v"(d6),"+v"(d7),"+v"(d8)                \
        : "v"(o0),"v"(o1),"v"(o2),"v"(o3),"v"(o4),"s"(sp))

// Pre-kernel: transpose+convert w1 [16][64][3][3] fp32 into A-fragment order (f16).
// Fragment (dij, ks): lane l holds A[m = l&15][k = ks*32 + 8*(l>>4) + j], j=0..7.
__global__ void prep_w1(const float* __restrict__ w1, unsigned short* __restrict__ wt) {
    const int dij = blockIdx.x >> 1;
    const int ks  = blockIdx.x & 1;
    const int l   = threadIdx.x;           // 0..63
    const int m   = l & 15;
    const int kb  = ks * 32 + 8 * (l >> 4);
    unsigned short v[8];
#pragma unroll
    for (int jj = 0; jj < 8; ++jj)
        v[jj] = f2h(w1[m * 576 + (kb + jj) * 9 + dij]);
    f16x8 o;
    __builtin_memcpy(&o, v, 16);
    ((f16x8*)wt)[blockIdx.x * 64 + l] = o;
}

__global__ __launch_bounds__(NT, 4)
void fasa_mfma(const float* __restrict__ x,
               const float* __restrict__ sobel_w,
               const unsigned short* __restrict__ wt,
               const float* __restrict__ b1,
               const float* __restrict__ w2,
               const float* __restrict__ b2,
               float* __restrict__ out)
{
    __shared__ __align__(16) char frq[PSS * 128];   // 46.2 KB, [pp][c] f16 swizzled

    const int t    = threadIdx.x;
    const int lane = t & 63;
    const int wave = __builtin_amdgcn_readfirstlane(t >> 6);

    // XCD-chunked swizzle (bijective, 3600 = 8*450)
    const int bid = blockIdx.x;
    const int win = (bid & 7) * 450 + (bid >> 3);   // b*900 + wh*30 + ww
    const int b   = win / 900;
    const int rem = win % 900;
    const int h0  = (rem / 30) * WSZ;
    const int w0  = (rem % 30) * WSZ;

    // ---- zero the 72 border rows of frq (interior rows all get written) ----
    for (int u = t; u < 72 * 8; u += NT) {
        int r = u >> 3, k = u & 7;
        int row;
        if      (r < 19) row = r;                   // pi == 0
        else if (r < 38) row = 342 + (r - 19);      // pi == 18
        else if (r < 55) row = (r - 37) * PS;       // pj == 0, pi 1..17
        else             row = (r - 54) * PS + 18;  // pj == 18, pi 1..17
        *(f32x4*)(frq + row * 128 + k * 16) = (f32x4){0.f, 0.f, 0.f, 0.f};
    }

    // ---- sobel weights: ALL channels share one 3x3 (tiled in setup) ----
    const float sw0 = sobel_w[0], sw1 = sobel_w[1], sw2 = sobel_w[2];
    const float sw3 = sobel_w[3], sw4 = sobel_w[4], sw5 = sobel_w[5];
    const float sw6 = sobel_w[6], sw7 = sobel_w[7], sw8 = sobel_w[8];
    // separable fast path: middle column zero, col0 = -col2 (true for Sobel)
    const bool fast = (sw1 == 0.f) && (sw4 == 0.f) && (sw7 == 0.f) &&
                      (sw0 == -sw2) && (sw3 == -sw5) && (sw6 == -sw8);
    const f16x2 sw2h = {(_Float16)sw2, (_Float16)sw2};
    const f16x2 sw5h = {(_Float16)sw5, (_Float16)sw5};
    const f16x2 sw8h = {(_Float16)sw8, (_Float16)sw8};

    // ---- staging: lane = (grp, j); pair = 2*wave + grp + 16*q, q = 0,1 ----
    const int j   = lane & 31;       // column, active when j < 17
    const int grp = lane >> 5;       // which pair of this wave's two
    const bool jac = (j < 17);

    // wave-uniform bases: channel 4*wave, then q/y offsets folded into saddr
    const float* sp00 = x + ((size_t)(b * 64 + 4 * wave)) * CH
                          + (size_t)h0 * 510 + w0;
    const float* sp01 = sp00 + (size_t)CH;        // +1 channel (y of pair)
    const float* sp10 = sp00 + (size_t)32 * CH;   // q=1
    const float* sp11 = sp10 + (size_t)CH;

    // per-lane voffsets: channel-pair offset + column + row pairs (4080*k)
    const unsigned v0 = (unsigned)((grp * 2 * CH + j) * 4);
    const unsigned vk0 = v0,           vk1 = v0 + 4080u,  vk2 = v0 + 8160u;
    const unsigned vk3 = v0 + 12240u,  vk4 = v0 + 16320u, vk5 = v0 + 20400u;
    const unsigned vk6 = v0 + 24480u,  vk7 = v0 + 28560u, vk8 = v0 + 32640u;

    // data regs, pre-zeroed at full exec so inactive lanes (j>=17) keep the
    // zero columns the DPP edge handling relies on (lanes 17/31/49/63).
    float xA[17], yA[17], xB[17], yB[17];
#pragma unroll
    for (int i = 0; i < 17; ++i) { xA[i] = 0.f; yA[i] = 0.f; xB[i] = 0.f; yB[i] = 0.f; }

    if (jac) {
        GLD8(xA[0],xA[1],xA[2],xA[3],xA[4],xA[5],xA[6],xA[7], vk0,vk1,vk2,vk3, sp00);
        GLD9(xA[8],xA[9],xA[10],xA[11],xA[12],xA[13],xA[14],xA[15],xA[16],
             vk4,vk5,vk6,vk7,vk8, sp00);
        GLD8(yA[0],yA[1],yA[2],yA[3],yA[4],yA[5],yA[6],yA[7], vk0,vk1,vk2,vk3, sp01);
        GLD9(yA[8],yA[9],yA[10],yA[11],yA[12],yA[13],yA[14],yA[15],yA[16],
             vk4,vk5,vk6,vk7,vk8, sp01);
        GLD8(xB[0],xB[1],xB[2],xB[3],xB[4],xB[5],xB[6],xB[7], vk0,vk1,vk2,vk3, sp10);
        GLD9(xB[8],xB[9],xB[10],xB[11],xB[12],xB[13],xB[14],xB[15],xB[16],
             vk4,vk5,vk6,vk7,vk8, sp10);
        GLD8(yB[0],yB[1],yB[2],yB[3],yB[4],yB[5],yB[6],yB[7], vk0,vk1,vk2,vk3, sp11);
        GLD9(yB[8],yB[9],yB[10],yB[11],yB[12],yB[13],yB[14],yB[15],yB[16],
             vk4,vk5,vk6,vk7,vk8, sp11);
    }

    auto DOSOBEL = [&](const float* xr, const float* yr, int q) {
        const int pr = 2 * wave + grp + 16 * q;       // pair index 0..31
        const int pairOff = pr * 4;                   // pair byte offset in frq row
        if (fast) {
            // pack both channels to f16x2 once per row, then:
            // h_i = sw2h*x_{i-1} + sw5h*x_i + sw8h*x_{i+1}  (3 pk-f16 ops)
            // o_i(j) = h_i(j+1) - h_i(j-1)  (2 DPP + 1 pk-sub on packed reg)
            f16x2 xh[17];
#pragma unroll
            for (int i = 0; i < 17; ++i)
                xh[i] = pkrtz(xr[i], yr[i]);
            const f16x2 zero = {(_Float16)0.f, (_Float16)0.f};
#pragma unroll
            for (int i = 0; i < 17; ++i) {
                f16x2 top = (i > 0)  ? xh[i - 1] : zero;
                f16x2 bot = (i < 16) ? xh[i + 1] : zero;
                f16x2 h = sw2h * top + sw5h * xh[i] + sw8h * bot;
                int hi;
                __builtin_memcpy(&hi, &h, 4);
                int sl = dpp_shl1_i(hi);
                int sr = dpp_shr1_i(hi);
                f16x2 hl, hr;
                __builtin_memcpy(&hl, &sl, 4);
                __builtin_memcpy(&hr, &sr, 4);
                f16x2 o = hl - hr;
                unsigned pkv;
                __builtin_memcpy(&pkv, &o, 4);
                if (jac)
                    *(unsigned*)(frq + swz(((i + 1) * PS + (j + 1)) * 128 + pairOff)) = pkv;
            }
        } else {
            // general 9-tap (f32 math, f16 pack)
#pragma unroll
            for (int i = 0; i < 17; ++i) {
                f32x2 top = { (i > 0  ? xr[i - 1] : 0.f), (i > 0  ? yr[i - 1] : 0.f) };
                f32x2 mid = { xr[i],                       yr[i] };
                f32x2 bot = { (i < 16 ? xr[i + 1] : 0.f), (i < 16 ? yr[i + 1] : 0.f) };
                f32x2 p0 = sw0 * top + sw3 * mid + sw6 * bot;
                f32x2 p1 = sw1 * top + sw4 * mid + sw7 * bot;
                f32x2 p2 = sw2 * top + sw5 * mid + sw8 * bot;
                f32x2 o;
                o.x = p1.x + dpp_shr1(p0.x) + dpp_shl1(p2.x);
                o.y = p1.y + dpp_shr1(p0.y) + dpp_shl1(p2.y);
                f16x2 oh = pkrtz(o.x, o.y);
                unsigned pkv;
                __builtin_memcpy(&pkv, &oh, 4);
                if (jac)
                    *(unsigned*)(frq + swz(((i + 1) * PS + (j + 1)) * 128 + pairOff)) = pkv;
            }
        }
    };

    // A ready (B's 34 still in flight under sobel A), then drain for B.
    asm volatile("s_waitcnt vmcnt(34)" ::: "memory");
    __builtin_amdgcn_sched_barrier(0);
    DOSOBEL(xA, yA, 0);
    asm volatile("s_waitcnt vmcnt(0)" ::: "memory");
    __builtin_amdgcn_sched_barrier(0);
    DOSOBEL(xB, yB, 1);

    // ---- W fragments + epilogue constants: issue before barrier ----
    f16x8 wf[18];
#pragma unroll
    for (int i = 0; i < 18; ++i)
        wf[i] = ((const f16x8*)wt)[i * 64 + lane];

    float b1v[4], w2v[4];
#pragma unroll
    for (int r = 0; r < 4; ++r) {
        int m = 4 * (lane >> 4) + r;
        b1v[r] = b1[m];
        w2v[r] = w2[m];
    }
    const float b2v = b2[0];

    __syncthreads();

    // ---- conv1 via MFMA: wave w handles pixel tiles {w, w+8, w+16} ----
    const int n   = lane & 15;          // pixel within tile (MFMA N)
    const int g16 = (lane >> 4) * 16;   // 8-channel chunk byte offset
    const int DOFF[9] = {0, 1, 2, PS, PS + 1, PS + 2, 2 * PS, 2 * PS + 1, 2 * PS + 2};

#pragma unroll 1
    for (int nt = wave; nt < 19; nt += 8) {
        int p  = nt * 16 + n;
        int pv = p > 288 ? 288 : p;     // clamp dead lanes of last tile
        int pi = pv / 17, pj = pv - pi * 17;
        int base = (pi * PS + pj) * 128 + g16;

        f32x4 acc = {0.f, 0.f, 0.f, 0.f};
#pragma unroll
        for (int d = 0; d < 9; ++d) {
            int off = base + DOFF[d] * 128;
            f16x8 bfA = *(const f16x8*)(frq + swz(off));
            f16x8 bfB = *(const f16x8*)(frq + swz(off + 64));
            acc = __builtin_amdgcn_mfma_f32_16x16x32_f16(wf[2 * d],     bfA, acc, 0, 0, 0);
            acc = __builtin_amdgcn_mfma_f32_16x16x32_f16(wf[2 * d + 1], bfB, acc, 0, 0, 0);
        }

        float part = 0.f;
#pragma unroll
        for (int r = 0; r < 4; ++r)
            part = fmaf(w2v[r], fmaxf(acc[r] + b1v[r], 0.f), part);
        part += __shfl_xor(part, 16);
        part += __shfl_xor(part, 32);

        if (lane < 16 && p < 289) {
            float pre = part + b2v;
            float s = 1.f / (1.f + expf(-pre));
            s = fminf(fmaxf(s, 0.05f), 0.95f);
            out[((size_t)(b * 510 + h0 + pi)) * 510 + (w0 + pj)] = s;
        }
    }
}

extern "C" void kernel_launch(void* const* d_in, const int* in_sizes, int n_in,
                              void* d_out, int out_size, void* d_ws, size_t ws_size,
                              hipStream_t stream) {
    const float* x       = (const float*)d_in[0];
    const float* sobel_w = (const float*)d_in[1];
    const float* w1      = (const float*)d_in[2];
    const float* b1      = (const float*)d_in[3];
    const float* w2      = (const float*)d_in[4];
    const float* b2      = (const float*)d_in[5];
    float* out = (float*)d_out;
    unsigned short* wtab = (unsigned short*)d_ws;   // 18*64*16 = 18432 B

    prep_w1<<<dim3(18), dim3(64), 0, stream>>>(w1, wtab);
    fasa_mfma<<<dim3(3600), dim3(NT), 0, stream>>>(x, sobel_w, wtab, b1, w2, b2, out);
}